// Round 2
// baseline (48256.595 us; speedup 1.0000x reference)
//
#include <hip/hip_runtime.h>

// Problem constants
#define NB   64          // B
#define NT   256         // T
#define NC   512         // C
#define NK   1024        // K codes per layer
#define NQ   6           // layers
#define NROWS (NB*NT)    // 16384
#define QOUT_ELEMS 8388608   // B*C*T
#define IDX_ELEMS  98304     // B*T*Q

// ws layout (bytes)
#define WS_BEST   0           // u64[16384]      (128 KiB)
#define WS_COUNTS 131072      // u32[1024]       (4 KiB)
#define WS_CSUM   135168      // float[6] raw commit sums
#define WS_CMEAN  135192      // float[6]
#define WS_PERP   135216      // float[6]
#define WS_CBN    135296      // float[6*1024] half-norms

// -------- codebook half-norms for all layers --------
__global__ void vq_cbnorm(const float* __restrict__ cb, float* __restrict__ cbn) {
    int lane = threadIdx.x & 63, wid = threadIdx.x >> 6;
    int code = blockIdx.x * 4 + wid;                    // grid 1536 -> 6144 codes
    const float4* p = (const float4*)(cb + (size_t)code * NC);
    float4 v1 = p[lane], v2 = p[lane + 64];
    float s = v1.x*v1.x + v1.y*v1.y + v1.z*v1.z + v1.w*v1.w
            + v2.x*v2.x + v2.y*v2.y + v2.z*v2.z + v2.w*v2.w;
    #pragma unroll
    for (int off = 32; off; off >>= 1) s += __shfl_down(s, off, 64);
    if (lane == 0) cbn[code] = 0.5f * s;
}

// -------- fused distance GEMM + argmin --------
// grid (128 rowblocks, 8 codegroups), 256 threads, __launch_bounds__(256,4)
// Block tile: 128 rows x 128 codes, micro-tile 8x8 (float2 operands), C-chunk 32.
// LDS: xs in [c][t] layout (conflict-free float4 staging, broadcast reads);
//      bs in [k][c] with pad 34 (conflict-free b64 reads).
// score = ||cb||^2/2 - x.cb  (monotone in true distance)
#define XS_LD 132
#define BS_LD 34
#define XS_BYTES (32*XS_LD*4)    // 16896
#define BS_BYTES (128*BS_LD*4)   // 17408

__global__ __launch_bounds__(256, 4) void vq_dist(
    const float* __restrict__ src,     // residual (B,C,T)
    const float* __restrict__ cb,      // layer codebook (K,C)
    const float* __restrict__ cbn,     // layer half-norms (K)
    unsigned long long* __restrict__ best,
    unsigned int* __restrict__ counts,
    float* __restrict__ commit_slot)
{
    const int rb  = blockIdx.x;        // 0..127
    const int cg  = blockIdx.y;        // 0..7
    const int tid = threadIdx.x;
    // fold zero-init of counts/commit for the NEXT (update) kernel into block (0,0)
    if (rb == 0 && cg == 0) {
        for (int i = tid; i < NK; i += 256) counts[i] = 0u;
        if (tid == 0) *commit_slot = 0.f;
    }
    __shared__ __align__(16) char smem[XS_BYTES + BS_BYTES];
    float (*xs)[XS_LD] = (float(*)[XS_LD])smem;                 // [32 c][128 t +pad]
    float (*bs)[BS_LD] = (float(*)[BS_LD])(smem + XS_BYTES);    // [128 k][32 c +pad]

    const int tcol = tid & 15;         // code group (8 codes, stride 16)
    const int trow = tid >> 4;         // row group (8 rows contiguous)
    const int r0   = trow * 8;
    const int b  = rb >> 1;
    const int t0 = (rb & 1) << 7;      // t tile of 128
    const int kbase = cg * 128;
    const float* xbase = src + (size_t)b * (NC * NT) + t0;

    float acc[8][8];
    #pragma unroll
    for (int i = 0; i < 8; ++i)
        #pragma unroll
        for (int j = 0; j < 8; ++j) acc[i][j] = 0.f;

    for (int cc = 0; cc < NC; cc += 32) {
        __syncthreads();
        // stage A: [c][t] layout, direct float4 writes (no transpose, no conflicts)
        #pragma unroll
        for (int i = 0; i < 4; ++i) {
            int f   = tid + (i << 8);     // 0..1023
            int c_l = f >> 5;             // 0..31
            int tf  = f & 31;             // t in units of 4
            float4 v = *(const float4*)(xbase + (size_t)(cc + c_l) * NT + (tf << 2));
            *(float4*)&xs[c_l][tf << 2] = v;
        }
        // stage B: 128 k x 32 c from (K,C): coalesced along c, b64 writes (8B aligned)
        #pragma unroll
        for (int i = 0; i < 4; ++i) {
            int f   = tid + (i << 8);
            int k_l = f >> 3;             // 0..127
            int cs  = f & 7;              // c in units of 4
            float4 v = *(const float4*)(cb + (size_t)(kbase + k_l) * NC + cc + (cs << 2));
            *(float2*)&bs[k_l][(cs << 2) + 0] = make_float2(v.x, v.y);
            *(float2*)&bs[k_l][(cs << 2) + 2] = make_float2(v.z, v.w);
        }
        __syncthreads();
        // micro-kernel: c-pairs; operands as float2 (keeps VGPR <= 128, no spill)
        #pragma unroll
        for (int c2 = 0; c2 < 16; ++c2) {
            const int c = c2 * 2;
            float2 av[4], av2[4], bv[8];
            #pragma unroll
            for (int ip = 0; ip < 4; ++ip) {
                av[ip]  = *(const float2*)&xs[c + 0][r0 + 2 * ip];
                av2[ip] = *(const float2*)&xs[c + 1][r0 + 2 * ip];
            }
            #pragma unroll
            for (int j = 0; j < 8; ++j)
                bv[j] = *(const float2*)&bs[tcol + 16 * j][c];
            #pragma unroll
            for (int ip = 0; ip < 4; ++ip)
                #pragma unroll
                for (int j = 0; j < 8; ++j) {
                    acc[2*ip+0][j] += av[ip].x * bv[j].x + av2[ip].x * bv[j].y;
                    acc[2*ip+1][j] += av[ip].y * bv[j].x + av2[ip].y * bv[j].y;
                }
        }
    }

    // epilogue: score + running argmin (ascending j keeps lowest k on ties)
    float bsc[8]; int bki[8];
    #pragma unroll
    for (int i = 0; i < 8; ++i) { bsc[i] = 3.402823466e38f; bki[i] = 0; }
    #pragma unroll
    for (int j = 0; j < 8; ++j) {
        int kg = kbase + tcol + 16 * j;
        float cn = cbn[kg];
        #pragma unroll
        for (int i = 0; i < 8; ++i) {
            float s = cn - acc[i][j];
            if (s < bsc[i]) { bsc[i] = s; bki[i] = kg; }
        }
    }
    __syncthreads();
    // reuse smem for the reduction
    float (*red_s)[17] = (float(*)[17])smem;
    int   (*red_i)[17] = (int(*)[17])(smem + 128 * 17 * 4);
    #pragma unroll
    for (int i = 0; i < 8; ++i) {
        red_s[r0 + i][tcol] = bsc[i];
        red_i[r0 + i][tcol] = bki[i];
    }
    __syncthreads();
    if (tid < 128) {
        float s = red_s[tid][0]; int k = red_i[tid][0];
        #pragma unroll
        for (int e = 1; e < 16; ++e) {
            float s2 = red_s[tid][e]; int k2 = red_i[tid][e];
            if (s2 < s || (s2 == s && k2 < k)) { s = s2; k = k2; }
        }
        unsigned int u = __float_as_uint(s);
        u = (u & 0x80000000u) ? ~u : (u | 0x80000000u);   // order-preserving map
        unsigned long long key = ((unsigned long long)u << 32) | (unsigned int)k;
        atomicMin(&best[(size_t)rb * 128 + tid], key);
    }
}

// -------- gather + residual update + commit + histogram + index output --------
// grid 256 blocks (64 rows each), 256 threads
__global__ __launch_bounds__(256) void vq_update(
    const float* __restrict__ src,    // residual before (x for q=0), (B,C,T)
    float* __restrict__ dst,          // residual after (d_out qout slot)
    const float* __restrict__ cb,
    const unsigned long long* __restrict__ best,
    unsigned int* __restrict__ counts,
    float* __restrict__ commit_slot,
    float* __restrict__ out_idx,
    int q)
{
    const int rb = blockIdx.x, tid = threadIdx.x;
    const int b = rb >> 2, t0 = (rb & 3) << 6;
    const int row0 = rb * 64;
    __shared__ int s_idx[64];
    __shared__ __align__(16) float qt[64][68];   // [c_local][t_local]
    __shared__ float wsum[4];
    if (tid < 64) {
        unsigned long long key = best[row0 + tid];
        int idx = (int)(key & 0xFFFFFFFFull);
        s_idx[tid] = idx;
        out_idx[(size_t)(row0 + tid) * NQ + q] = (float)idx;
        atomicAdd(&counts[idx], 1u);
    }
    __syncthreads();
    float csum = 0.f;
    const size_t base = (size_t)b * (NC * NT) + t0;
    for (int ct = 0; ct < 8; ++ct) {             // c chunks of 64
        if (ct) __syncthreads();
        // fill qt with cb[idx[r]][ct*64 .. +64), transposed to [c][t]
        #pragma unroll
        for (int i = 0; i < 4; ++i) {
            int f = tid + (i << 8);              // 0..1023
            int r = f >> 4, cf = f & 15;
            float4 v = *(const float4*)(cb + (size_t)s_idx[r] * NC + ct * 64 + (cf << 2));
            qt[(cf << 2) + 0][r] = v.x;
            qt[(cf << 2) + 1][r] = v.y;
            qt[(cf << 2) + 2][r] = v.z;
            qt[(cf << 2) + 3][r] = v.w;
        }
        __syncthreads();
        // residual RMW, coalesced along t
        #pragma unroll
        for (int i = 0; i < 4; ++i) {
            int f = tid + (i << 8);
            int c_l = f >> 4, tf = f & 15;
            size_t o = base + (size_t)(ct * 64 + c_l) * NT + (tf << 2);
            float4 r4 = *(const float4*)(src + o);
            float4 q4 = *(const float4*)&qt[c_l][tf << 2];
            float4 n;
            n.x = r4.x - q4.x; n.y = r4.y - q4.y; n.z = r4.z - q4.z; n.w = r4.w - q4.w;
            *(float4*)(dst + o) = n;
            csum += n.x*n.x + n.y*n.y + n.z*n.z + n.w*n.w;
        }
    }
    #pragma unroll
    for (int off = 32; off; off >>= 1) csum += __shfl_down(csum, off, 64);
    if ((tid & 63) == 0) wsum[tid >> 6] = csum;
    __syncthreads();
    if (tid == 0) atomicAdd(commit_slot, wsum[0] + wsum[1] + wsum[2] + wsum[3]);
}

// -------- perplexity + commit mean per layer; final means at q==5 --------
__global__ void vq_stats(const unsigned int* __restrict__ counts,
                         float* __restrict__ csum, float* __restrict__ cmean,
                         float* __restrict__ perp, float* __restrict__ out_tail, int q)
{
    const int tid = threadIdx.x;   // 1024
    float p = (float)counts[tid] * (1.f / (float)NROWS);
    float v = p * logf(p + 1e-7f);
    #pragma unroll
    for (int off = 32; off; off >>= 1) v += __shfl_down(v, off, 64);
    __shared__ float red[16];
    if ((tid & 63) == 0) red[tid >> 6] = v;
    __syncthreads();
    if (tid == 0) {
        float S = 0.f;
        #pragma unroll
        for (int i = 0; i < 16; ++i) S += red[i];
        perp[q]  = expf(-S);
        cmean[q] = csum[q] * (1.f / ((float)NROWS * (float)NC));
        if (q == NQ - 1) {
            float mc = 0.f, mp = 0.f;
            for (int i = 0; i < NQ; ++i) { mc += cmean[i]; mp += perp[i]; }
            out_tail[0] = mc / (float)NQ;
            out_tail[1] = mp / (float)NQ;
        }
    }
}

// -------- qout = x - residual_final (elementwise, in place) --------
__global__ void vq_finalize(const float* __restrict__ x, float* __restrict__ res, int n4) {
    int i = blockIdx.x * blockDim.x + threadIdx.x;
    if (i < n4) {
        float4 a = ((const float4*)x)[i];
        float4 r = ((float4*)res)[i];
        float4 o;
        o.x = a.x - r.x; o.y = a.y - r.y; o.z = a.z - r.z; o.w = a.w - r.w;
        ((float4*)res)[i] = o;
    }
}

extern "C" void kernel_launch(void* const* d_in, const int* in_sizes, int n_in,
                              void* d_out, int out_size, void* d_ws, size_t ws_size,
                              hipStream_t stream) {
    const float* x  = (const float*)d_in[0];
    const float* cb = (const float*)d_in[1];       // (Q,K,C)
    float* out      = (float*)d_out;
    float* res      = out;                          // residual lives in qout slot
    float* out_idx  = out + QOUT_ELEMS;
    float* out_tail = out + QOUT_ELEMS + IDX_ELEMS;
    char* ws = (char*)d_ws;
    unsigned long long* best = (unsigned long long*)(ws + WS_BEST);
    unsigned int* counts = (unsigned int*)(ws + WS_COUNTS);
    float* csum  = (float*)(ws + WS_CSUM);
    float* cmean = (float*)(ws + WS_CMEAN);
    float* perp  = (float*)(ws + WS_PERP);
    float* cbn   = (float*)(ws + WS_CBN);

    vq_cbnorm<<<1536, 256, 0, stream>>>(cb, cbn);
    for (int q = 0; q < NQ; ++q) {
        hipMemsetAsync(best, 0xFF, NROWS * sizeof(unsigned long long), stream);
        const float* src = (q == 0) ? x : res;
        const float* cbq = cb + (size_t)q * NK * NC;
        vq_dist<<<dim3(128, 8), 256, 0, stream>>>(src, cbq, cbn + q * NK,
                                                  best, counts, csum + q);
        vq_update<<<256, 256, 0, stream>>>(src, res, cbq, best, counts,
                                           csum + q, out_idx, q);
        vq_stats<<<1, 1024, 0, stream>>>(counts, csum, cmean, perp, out_tail, q);
    }
    vq_finalize<<<8192, 256, 0, stream>>>(x, res, QOUT_ELEMS / 4);
}

// Round 3
// 1514.915 us; speedup vs baseline: 31.8543x; 31.8543x over previous
//
#include <hip/hip_runtime.h>

// Problem constants
#define NB   64          // B
#define NT   256         // T
#define NC   512         // C
#define NK   1024        // K codes per layer
#define NQ   6           // layers
#define NROWS (NB*NT)    // 16384
#define QOUT_ELEMS 8388608   // B*C*T
#define IDX_ELEMS  98304     // B*T*Q

// ws layout (bytes)
#define WS_BEST   0           // u64[16384]      (128 KiB)
#define WS_COUNTS 131072      // u32[1024]       (4 KiB)
#define WS_CSUM   135168      // float[6] raw commit sums
#define WS_CMEAN  135192      // float[6]
#define WS_PERP   135216      // float[6]
#define WS_CBN    135296      // float[6*1024] half-norms

// -------- codebook half-norms for all layers --------
__global__ void vq_cbnorm(const float* __restrict__ cb, float* __restrict__ cbn) {
    int lane = threadIdx.x & 63, wid = threadIdx.x >> 6;
    int code = blockIdx.x * 4 + wid;                    // grid 1536 -> 6144 codes
    const float4* p = (const float4*)(cb + (size_t)code * NC);
    float4 v1 = p[lane], v2 = p[lane + 64];
    float s = v1.x*v1.x + v1.y*v1.y + v1.z*v1.z + v1.w*v1.w
            + v2.x*v2.x + v2.y*v2.y + v2.z*v2.z + v2.w*v2.w;
    #pragma unroll
    for (int off = 32; off; off >>= 1) s += __shfl_down(s, off, 64);
    if (lane == 0) cbn[code] = 0.5f * s;
}

// -------- fused distance GEMM + argmin --------
// grid (128 rowblocks, 8 codegroups), 256 threads, NO min-occupancy hint
// (round 2 lesson: __launch_bounds__(256,4) forced VGPR=64 -> total spill).
// Block tile: 128 rows x 128 codes, micro-tile 8x8, C-chunk 32, b128 LDS ops.
// LDS: xs [c][t] pad 132 (16B-aligned rows, conflict-free staging+reads);
//      bs [k][c] pad 36  (16B-aligned float4 rows, 2-way-max read aliasing).
// score = ||cb||^2/2 - x.cb  (monotone in true distance)
#define XS_LD 132
#define BS_LD 36
#define XS_BYTES (32*XS_LD*4)    // 16896
#define BS_BYTES (128*BS_LD*4)   // 18432

__global__ __launch_bounds__(256) void vq_dist(
    const float* __restrict__ src,     // residual (B,C,T)
    const float* __restrict__ cb,      // layer codebook (K,C)
    const float* __restrict__ cbn,     // layer half-norms (K)
    unsigned long long* __restrict__ best,
    unsigned int* __restrict__ counts,
    float* __restrict__ commit_slot)
{
    const int rb  = blockIdx.x;        // 0..127
    const int cg  = blockIdx.y;        // 0..7
    const int tid = threadIdx.x;
    // fold zero-init of counts/commit for the NEXT (update) kernel into block (0,0)
    if (rb == 0 && cg == 0) {
        for (int i = tid; i < NK; i += 256) counts[i] = 0u;
        if (tid == 0) *commit_slot = 0.f;
    }
    __shared__ __align__(16) char smem[XS_BYTES + BS_BYTES];
    float (*xs)[XS_LD] = (float(*)[XS_LD])smem;                 // [32 c][128 t +pad]
    float (*bs)[BS_LD] = (float(*)[BS_LD])(smem + XS_BYTES);    // [128 k][32 c +pad]

    const int tcol = tid & 15;         // code group (8 codes, stride 16)
    const int trow = tid >> 4;         // row group (8 rows contiguous)
    const int r0   = trow * 8;
    const int b  = rb >> 1;
    const int t0 = (rb & 1) << 7;      // t tile of 128
    const int kbase = cg * 128;
    const float* xbase = src + (size_t)b * (NC * NT) + t0;

    float acc[8][8];
    #pragma unroll
    for (int i = 0; i < 8; ++i)
        #pragma unroll
        for (int j = 0; j < 8; ++j) acc[i][j] = 0.f;

    for (int cc = 0; cc < NC; cc += 32) {
        __syncthreads();
        // stage A: [c][t] layout, direct float4 writes (no transpose, no conflicts)
        #pragma unroll
        for (int i = 0; i < 4; ++i) {
            int f   = tid + (i << 8);     // 0..1023
            int c_l = f >> 5;             // 0..31
            int tf  = f & 31;             // t in units of 4
            float4 v = *(const float4*)(xbase + (size_t)(cc + c_l) * NT + (tf << 2));
            *(float4*)&xs[c_l][tf << 2] = v;
        }
        // stage B: 128 k x 32 c from (K,C): coalesced along c, 16B-aligned b128 writes
        #pragma unroll
        for (int i = 0; i < 4; ++i) {
            int f   = tid + (i << 8);
            int k_l = f >> 3;             // 0..127
            int cs  = f & 7;              // c in units of 4
            float4 v = *(const float4*)(cb + (size_t)(kbase + k_l) * NC + cc + (cs << 2));
            *(float4*)&bs[k_l][cs << 2] = v;
        }
        __syncthreads();
        // micro-kernel: c-quads, all-b128 operand reads, unroll 1 (bounds VGPR live set)
        #pragma unroll 1
        for (int cq = 0; cq < 8; ++cq) {
            const int c = cq << 2;
            float4 alo[4], ahi[4], bv[8];
            #pragma unroll
            for (int u = 0; u < 4; ++u) {
                alo[u] = *(const float4*)&xs[c + u][r0];
                ahi[u] = *(const float4*)&xs[c + u][r0 + 4];
            }
            #pragma unroll
            for (int j = 0; j < 8; ++j)
                bv[j] = *(const float4*)&bs[tcol + 16 * j][c];
            #pragma unroll
            for (int j = 0; j < 8; ++j) {
                #pragma unroll
                for (int u = 0; u < 4; ++u) {
                    const float bw = (u == 0) ? bv[j].x : (u == 1) ? bv[j].y
                                   : (u == 2) ? bv[j].z : bv[j].w;
                    acc[0][j] += alo[u].x * bw;
                    acc[1][j] += alo[u].y * bw;
                    acc[2][j] += alo[u].z * bw;
                    acc[3][j] += alo[u].w * bw;
                    acc[4][j] += ahi[u].x * bw;
                    acc[5][j] += ahi[u].y * bw;
                    acc[6][j] += ahi[u].z * bw;
                    acc[7][j] += ahi[u].w * bw;
                }
            }
        }
    }

    // epilogue: score + running argmin (ascending j keeps lowest k on ties)
    float bsc[8]; int bki[8];
    #pragma unroll
    for (int i = 0; i < 8; ++i) { bsc[i] = 3.402823466e38f; bki[i] = 0; }
    #pragma unroll
    for (int j = 0; j < 8; ++j) {
        int kg = kbase + tcol + 16 * j;
        float cn = cbn[kg];
        #pragma unroll
        for (int i = 0; i < 8; ++i) {
            float s = cn - acc[i][j];
            if (s < bsc[i]) { bsc[i] = s; bki[i] = kg; }
        }
    }
    __syncthreads();
    // reuse smem for the reduction
    float (*red_s)[17] = (float(*)[17])smem;
    int   (*red_i)[17] = (int(*)[17])(smem + 128 * 17 * 4);
    #pragma unroll
    for (int i = 0; i < 8; ++i) {
        red_s[r0 + i][tcol] = bsc[i];
        red_i[r0 + i][tcol] = bki[i];
    }
    __syncthreads();
    if (tid < 128) {
        float s = red_s[tid][0]; int k = red_i[tid][0];
        #pragma unroll
        for (int e = 1; e < 16; ++e) {
            float s2 = red_s[tid][e]; int k2 = red_i[tid][e];
            if (s2 < s || (s2 == s && k2 < k)) { s = s2; k = k2; }
        }
        unsigned int u = __float_as_uint(s);
        u = (u & 0x80000000u) ? ~u : (u | 0x80000000u);   // order-preserving map
        unsigned long long key = ((unsigned long long)u << 32) | (unsigned int)k;
        atomicMin(&best[(size_t)rb * 128 + tid], key);
    }
}

// -------- gather + residual update + commit + histogram + index output --------
// grid 256 blocks (64 rows each), 256 threads
__global__ __launch_bounds__(256) void vq_update(
    const float* __restrict__ src,    // residual before (x for q=0), (B,C,T)
    float* __restrict__ dst,          // residual after (d_out qout slot)
    const float* __restrict__ cb,
    const unsigned long long* __restrict__ best,
    unsigned int* __restrict__ counts,
    float* __restrict__ commit_slot,
    float* __restrict__ out_idx,
    int q)
{
    const int rb = blockIdx.x, tid = threadIdx.x;
    const int b = rb >> 2, t0 = (rb & 3) << 6;
    const int row0 = rb * 64;
    __shared__ int s_idx[64];
    __shared__ __align__(16) float qt[64][68];   // [c_local][t_local]
    __shared__ float wsum[4];
    if (tid < 64) {
        unsigned long long key = best[row0 + tid];
        int idx = (int)(key & 0xFFFFFFFFull);
        s_idx[tid] = idx;
        out_idx[(size_t)(row0 + tid) * NQ + q] = (float)idx;
        atomicAdd(&counts[idx], 1u);
    }
    __syncthreads();
    float csum = 0.f;
    const size_t base = (size_t)b * (NC * NT) + t0;
    for (int ct = 0; ct < 8; ++ct) {             // c chunks of 64
        if (ct) __syncthreads();
        // fill qt with cb[idx[r]][ct*64 .. +64), transposed to [c][t]
        #pragma unroll
        for (int i = 0; i < 4; ++i) {
            int f = tid + (i << 8);              // 0..1023
            int r = f >> 4, cf = f & 15;
            float4 v = *(const float4*)(cb + (size_t)s_idx[r] * NC + ct * 64 + (cf << 2));
            qt[(cf << 2) + 0][r] = v.x;
            qt[(cf << 2) + 1][r] = v.y;
            qt[(cf << 2) + 2][r] = v.z;
            qt[(cf << 2) + 3][r] = v.w;
        }
        __syncthreads();
        // residual RMW, coalesced along t
        #pragma unroll
        for (int i = 0; i < 4; ++i) {
            int f = tid + (i << 8);
            int c_l = f >> 4, tf = f & 15;
            size_t o = base + (size_t)(ct * 64 + c_l) * NT + (tf << 2);
            float4 r4 = *(const float4*)(src + o);
            float4 q4 = *(const float4*)&qt[c_l][tf << 2];
            float4 n;
            n.x = r4.x - q4.x; n.y = r4.y - q4.y; n.z = r4.z - q4.z; n.w = r4.w - q4.w;
            *(float4*)(dst + o) = n;
            csum += n.x*n.x + n.y*n.y + n.z*n.z + n.w*n.w;
        }
    }
    #pragma unroll
    for (int off = 32; off; off >>= 1) csum += __shfl_down(csum, off, 64);
    if ((tid & 63) == 0) wsum[tid >> 6] = csum;
    __syncthreads();
    if (tid == 0) atomicAdd(commit_slot, wsum[0] + wsum[1] + wsum[2] + wsum[3]);
}

// -------- perplexity + commit mean per layer; final means at q==5 --------
__global__ void vq_stats(const unsigned int* __restrict__ counts,
                         float* __restrict__ csum, float* __restrict__ cmean,
                         float* __restrict__ perp, float* __restrict__ out_tail, int q)
{
    const int tid = threadIdx.x;   // 1024
    float p = (float)counts[tid] * (1.f / (float)NROWS);
    float v = p * logf(p + 1e-7f);
    #pragma unroll
    for (int off = 32; off; off >>= 1) v += __shfl_down(v, off, 64);
    __shared__ float red[16];
    if ((tid & 63) == 0) red[tid >> 6] = v;
    __syncthreads();
    if (tid == 0) {
        float S = 0.f;
        #pragma unroll
        for (int i = 0; i < 16; ++i) S += red[i];
        perp[q]  = expf(-S);
        cmean[q] = csum[q] * (1.f / ((float)NROWS * (float)NC));
        if (q == NQ - 1) {
            float mc = 0.f, mp = 0.f;
            for (int i = 0; i < NQ; ++i) { mc += cmean[i]; mp += perp[i]; }
            out_tail[0] = mc / (float)NQ;
            out_tail[1] = mp / (float)NQ;
        }
    }
}

// -------- qout = x - residual_final (elementwise, in place) --------
__global__ void vq_finalize(const float* __restrict__ x, float* __restrict__ res, int n4) {
    int i = blockIdx.x * blockDim.x + threadIdx.x;
    if (i < n4) {
        float4 a = ((const float4*)x)[i];
        float4 r = ((float4*)res)[i];
        float4 o;
        o.x = a.x - r.x; o.y = a.y - r.y; o.z = a.z - r.z; o.w = a.w - r.w;
        ((float4*)res)[i] = o;
    }
}

extern "C" void kernel_launch(void* const* d_in, const int* in_sizes, int n_in,
                              void* d_out, int out_size, void* d_ws, size_t ws_size,
                              hipStream_t stream) {
    const float* x  = (const float*)d_in[0];
    const float* cb = (const float*)d_in[1];       // (Q,K,C)
    float* out      = (float*)d_out;
    float* res      = out;                          // residual lives in qout slot
    float* out_idx  = out + QOUT_ELEMS;
    float* out_tail = out + QOUT_ELEMS + IDX_ELEMS;
    char* ws = (char*)d_ws;
    unsigned long long* best = (unsigned long long*)(ws + WS_BEST);
    unsigned int* counts = (unsigned int*)(ws + WS_COUNTS);
    float* csum  = (float*)(ws + WS_CSUM);
    float* cmean = (float*)(ws + WS_CMEAN);
    float* perp  = (float*)(ws + WS_PERP);
    float* cbn   = (float*)(ws + WS_CBN);

    vq_cbnorm<<<1536, 256, 0, stream>>>(cb, cbn);
    for (int q = 0; q < NQ; ++q) {
        hipMemsetAsync(best, 0xFF, NROWS * sizeof(unsigned long long), stream);
        const float* src = (q == 0) ? x : res;
        const float* cbq = cb + (size_t)q * NK * NC;
        vq_dist<<<dim3(128, 8), 256, 0, stream>>>(src, cbq, cbn + q * NK,
                                                  best, counts, csum + q);
        vq_update<<<256, 256, 0, stream>>>(src, res, cbq, best, counts,
                                           csum + q, out_idx, q);
        vq_stats<<<1, 1024, 0, stream>>>(counts, csum, cmean, perp, out_tail, q);
    }
    vq_finalize<<<8192, 256, 0, stream>>>(x, res, QOUT_ELEMS / 4);
}

// Round 5
// 1160.630 us; speedup vs baseline: 41.5779x; 1.3053x over previous
//
#include <hip/hip_runtime.h>

typedef short bf16x8 __attribute__((ext_vector_type(8)));
typedef float f32x4  __attribute__((ext_vector_type(4)));

// Problem constants
#define NB   64
#define NT   256
#define NC   512
#define NK   1024
#define NQ   6
#define NROWS (NB*NT)        // 16384
#define QOUT_ELEMS 8388608   // B*C*T
#define IDX_ELEMS  98304     // B*T*Q
#define DELTA 0.0625f        // candidate window (>=10x the 6-sigma approx error)

// ws layout (bytes) — total ~46.4 MiB (round-4-proven scale)
#define WS_CAND   0                        // u32[16384*32] = 2 MiB
#define WS_CCNT   0x200000                 // u32[16384]
#define WS_BIDX   0x210000                 // i32[16384]
#define WS_COUNTS 0x220000                 // u32[1024]
#define WS_CSUM   0x221000                 // f32[6]
#define WS_CMEAN  0x221020
#define WS_PERP   0x221040
#define WS_CBN    0x222000                 // f32[6144]
#define WS_XHI    0x230000                 // ushort[16384*512] (r,c), 16 MiB
#define WS_XLO    (WS_XHI + 16777216)
#define WS_CBHI   (WS_XLO + 16777216)      // ushort[6144*512], 6 MiB
#define WS_CBLO   (WS_CBHI + 6291456)

// bf16 split helpers (RNE; data is gaussian, no inf/nan)
__device__ __forceinline__ unsigned short f2bf(float f) {
    unsigned u = __float_as_uint(f);
    return (unsigned short)((u + 0x7FFFu + ((u >> 16) & 1u)) >> 16);
}
__device__ __forceinline__ float bf2f(unsigned short h) {
    return __uint_as_float(((unsigned)h) << 16);
}

__device__ __forceinline__ void load_lds16(const unsigned short* g, unsigned short* l) {
    __builtin_amdgcn_global_load_lds(
        (const __attribute__((address_space(1))) unsigned int*)g,
        (__attribute__((address_space(3))) unsigned int*)l,
        16, 0, 0);
}

// -------- codebook conversion (all 6 layers) + half-norms --------
__global__ __launch_bounds__(256) void vq_cvt_cb(const float* __restrict__ cb,
                                                 unsigned short* __restrict__ cbhi,
                                                 unsigned short* __restrict__ cblo,
                                                 float* __restrict__ cbn) {
    int lane = threadIdx.x & 63, wid = threadIdx.x >> 6;
    int code = blockIdx.x * 4 + wid;                 // 0..6143
    const float* row = cb + (size_t)code * NC;
    float4 v0 = *(const float4*)(row + lane * 8);
    float4 v1 = *(const float4*)(row + lane * 8 + 4);
    float vs[8] = {v0.x, v0.y, v0.z, v0.w, v1.x, v1.y, v1.z, v1.w};
    unsigned short h8[8], l8[8];
    float s = 0.f;
    #pragma unroll
    for (int j = 0; j < 8; ++j) {
        s += vs[j] * vs[j];
        unsigned short h = f2bf(vs[j]);
        h8[j] = h;
        l8[j] = f2bf(vs[j] - bf2f(h));
    }
    size_t o = (size_t)code * NC + lane * 8;
    ushort4 a, b;
    a.x = h8[0]; a.y = h8[1]; a.z = h8[2]; a.w = h8[3];
    b.x = h8[4]; b.y = h8[5]; b.z = h8[6]; b.w = h8[7];
    *(ushort4*)(cbhi + o) = a; *(ushort4*)(cbhi + o + 4) = b;
    a.x = l8[0]; a.y = l8[1]; a.z = l8[2]; a.w = l8[3];
    b.x = l8[4]; b.y = l8[5]; b.z = l8[6]; b.w = l8[7];
    *(ushort4*)(cblo + o) = a; *(ushort4*)(cblo + o + 4) = b;
    #pragma unroll
    for (int off = 32; off; off >>= 1) s += __shfl_down(s, off, 64);
    if (lane == 0) cbn[code] = 0.5f * s;
}

// -------- x conversion: (B,C,T) fp32 -> (r=b*T+t, c) bf16 hi/lo --------
__global__ __launch_bounds__(256) void vq_cvt_x(const float* __restrict__ x,
                                                unsigned short* __restrict__ xhi,
                                                unsigned short* __restrict__ xlo) {
    __shared__ unsigned short hs[64][72], ls[64][72];
    int bx = blockIdx.x;
    int b = bx >> 5, tt = (bx >> 3) & 3, c0 = (bx & 7) << 6;
    int t0 = tt << 6, tid = threadIdx.x;
    const float* base = x + (size_t)b * (NC * NT) + t0;
    #pragma unroll
    for (int i = 0; i < 4; ++i) {
        int f = tid + (i << 8);
        int c_l = f >> 4, t4 = f & 15;
        float4 v = *(const float4*)(base + (size_t)(c0 + c_l) * NT + (t4 << 2));
        float vv[4] = {v.x, v.y, v.z, v.w};
        ushort4 hh, ll;
        unsigned short* hp = &hh.x; unsigned short* lp = &ll.x;
        #pragma unroll
        for (int j = 0; j < 4; ++j) {
            unsigned short h = f2bf(vv[j]);
            hp[j] = h; lp[j] = f2bf(vv[j] - bf2f(h));
        }
        *(ushort4*)&hs[c_l][t4 << 2] = hh;
        *(ushort4*)&ls[c_l][t4 << 2] = ll;
    }
    __syncthreads();
    int row0 = b * NT + t0;
    #pragma unroll
    for (int i = 0; i < 4; ++i) {
        int f = tid + (i << 8);
        int r_l = f >> 4, c4 = f & 15;
        ushort4 hh, ll;
        hh.x = hs[c4*4+0][r_l]; hh.y = hs[c4*4+1][r_l];
        hh.z = hs[c4*4+2][r_l]; hh.w = hs[c4*4+3][r_l];
        ll.x = ls[c4*4+0][r_l]; ll.y = ls[c4*4+1][r_l];
        ll.z = ls[c4*4+2][r_l]; ll.w = ls[c4*4+3][r_l];
        size_t o = (size_t)(row0 + r_l) * NC + c0 + (c4 << 2);
        *(ushort4*)(xhi + o) = hh;
        *(ushort4*)(xlo + o) = ll;
    }
}

// -------- MFMA approx distance + candidate emission --------
// grid (128 rowblocks, 8 codegroups), 256 threads = 4 waves.
// approx score = ||cb||^2/2 - (xh.ch + xh.cl + xl.ch); per row each wave emits
// codes within DELTA of its 64-code min (superset contains the true argmin).
__global__ __launch_bounds__(256) void vq_dist(
    const unsigned short* __restrict__ xhi, const unsigned short* __restrict__ xlo,
    const unsigned short* __restrict__ cbhi, const unsigned short* __restrict__ cblo,
    const float* __restrict__ cbn,
    unsigned int* __restrict__ cand, unsigned int* __restrict__ candcnt,
    unsigned int* __restrict__ counts, float* __restrict__ commit_slot)
{
    const int rb = blockIdx.x, cg = blockIdx.y, tid = threadIdx.x;
    if (rb == 0 && cg == 0) {     // init for rescore/update kernels
        for (int i = tid; i < NK; i += 256) counts[i] = 0u;
        if (tid == 0) *commit_slot = 0.f;
    }
    __shared__ unsigned short smem[16384];   // 4 segs of 4096: Ahi,Alo,Bhi,Blo [128][32]
    const int wave = tid >> 6, lane = tid & 63;
    const int idx16 = lane & 15, quad = lane >> 4;
    const int wm = wave >> 1, wn = wave & 1;
    const int m0 = rb * 128, n0 = cg * 128;

    const unsigned short* gbase; int rowb;
    if      (wave == 0) { gbase = xhi;  rowb = m0; }
    else if (wave == 1) { gbase = xlo;  rowb = m0; }
    else if (wave == 2) { gbase = cbhi; rowb = n0; }
    else                { gbase = cblo; rowb = n0; }
    const unsigned short* gsrc0 = gbase + (size_t)(rowb + (lane >> 2)) * NC + (lane & 3) * 8;
    unsigned short* lbase = &smem[wave * 4096 + lane * 8];

    f32x4 acc[4][4];
    #pragma unroll
    for (int a = 0; a < 4; ++a)
        #pragma unroll
        for (int c = 0; c < 4; ++c) acc[a][c] = (f32x4){0.f, 0.f, 0.f, 0.f};

    for (int cc = 0; cc < NC; cc += 32) {
        __syncthreads();
        #pragma unroll
        for (int i = 0; i < 8; ++i)
            load_lds16(gsrc0 + (size_t)(i * 16) * NC + cc, lbase + i * 512);
        __syncthreads();
        bf16x8 ah[4], al[4], bh[4], bl[4];
        #pragma unroll
        for (int mt = 0; mt < 4; ++mt) {
            int ro = (wm * 64 + mt * 16 + idx16) * 32 + quad * 8;
            ah[mt] = *(const bf16x8*)&smem[ro];
            al[mt] = *(const bf16x8*)&smem[4096 + ro];
        }
        #pragma unroll
        for (int nt = 0; nt < 4; ++nt) {
            int ro = (wn * 64 + nt * 16 + idx16) * 32 + quad * 8;
            bh[nt] = *(const bf16x8*)&smem[8192 + ro];
            bl[nt] = *(const bf16x8*)&smem[12288 + ro];
        }
        #pragma unroll
        for (int mt = 0; mt < 4; ++mt)
            #pragma unroll
            for (int nt = 0; nt < 4; ++nt) {
                acc[mt][nt] = __builtin_amdgcn_mfma_f32_16x16x32_bf16(ah[mt], bh[nt], acc[mt][nt], 0, 0, 0);
                acc[mt][nt] = __builtin_amdgcn_mfma_f32_16x16x32_bf16(ah[mt], bl[nt], acc[mt][nt], 0, 0, 0);
                acc[mt][nt] = __builtin_amdgcn_mfma_f32_16x16x32_bf16(al[mt], bh[nt], acc[mt][nt], 0, 0, 0);
            }
    }
    // epilogue: per D-row wave-min (16-lane butterfly), then delta-window emission
    float cn[4]; int ng[4];
    #pragma unroll
    for (int nt = 0; nt < 4; ++nt) {
        ng[nt] = n0 + wn * 64 + nt * 16 + idx16;
        cn[nt] = cbn[ng[nt]];
    }
    #pragma unroll
    for (int mt = 0; mt < 4; ++mt) {
        #pragma unroll
        for (int r = 0; r < 4; ++r) {
            float sc[4];
            float m = 3.402823466e38f;
            #pragma unroll
            for (int nt = 0; nt < 4; ++nt) {
                sc[nt] = cn[nt] - acc[mt][nt][r];
                m = fminf(m, sc[nt]);
            }
            #pragma unroll
            for (int sft = 1; sft < 16; sft <<= 1)
                m = fminf(m, __shfl_xor(m, sft, 64));
            m += DELTA;
            const int row = m0 + wm * 64 + mt * 16 + quad * 4 + r;
            #pragma unroll
            for (int nt = 0; nt < 4; ++nt) {
                if (sc[nt] <= m) {
                    unsigned slot = atomicAdd(&candcnt[row], 1u);
                    if (slot < 32u) cand[(size_t)row * 32 + slot] = (unsigned)ng[nt];
                }
            }
        }
    }
}

// -------- exact fp32 rescore of candidates: final argmin + histogram --------
// grid 1024 blocks (16 rows each), 256 threads = 4 waves, 4 rows/wave.
__global__ __launch_bounds__(256) void vq_rescore(
    const float* __restrict__ src,     // residual (B,C,T) current layer input
    const float* __restrict__ cb, const float* __restrict__ cbn,
    const unsigned int* __restrict__ cand, const unsigned int* __restrict__ candcnt,
    int* __restrict__ best_idx, float* __restrict__ out_idx,
    unsigned int* __restrict__ counts, int q)
{
    __shared__ float xl[16][512];      // [t_local][c], 32 KiB
    const int tid = threadIdx.x;
    const int b = blockIdx.x >> 4, t0 = (blockIdx.x & 15) << 4;
    const float* base = src + (size_t)b * (NC * NT) + t0;
    #pragma unroll
    for (int i = 0; i < 8; ++i) {
        int f = tid + (i << 8);
        int c = f >> 2, t4 = f & 3;
        float4 v = *(const float4*)(base + (size_t)c * NT + (t4 << 2));
        xl[(t4 << 2) + 0][c] = v.x; xl[(t4 << 2) + 1][c] = v.y;
        xl[(t4 << 2) + 2][c] = v.z; xl[(t4 << 2) + 3][c] = v.w;
    }
    __syncthreads();
    const int w = tid >> 6, lane = tid & 63;
    const int row0 = b * NT + t0;
    for (int rr = 0; rr < 4; ++rr) {
        const int tl = w * 4 + rr;
        const int row = row0 + tl;
        float4 xa = *(const float4*)&xl[tl][lane << 3];
        float4 xb = *(const float4*)&xl[tl][(lane << 3) + 4];
        int n = (int)candcnt[row]; if (n > 32) n = 32;
        float bs = 3.402823466e38f; int bi = 0x7FFFFFFF;
        for (int j = 0; j < n; ++j) {
            int code = (int)cand[(size_t)row * 32 + j];
            const float* cr = cb + (size_t)code * NC + (lane << 3);
            float4 ca = *(const float4*)cr;
            float4 cc = *(const float4*)(cr + 4);
            float s = xa.x*ca.x + xa.y*ca.y + xa.z*ca.z + xa.w*ca.w
                    + xb.x*cc.x + xb.y*cc.y + xb.z*cc.z + xb.w*cc.w;
            #pragma unroll
            for (int off = 1; off < 64; off <<= 1) s += __shfl_xor(s, off, 64);
            s = cbn[code] - s;
            if (s < bs || (s == bs && code < bi)) { bs = s; bi = code; }
        }
        if (lane == 0) {
            best_idx[row] = bi;
            out_idx[(size_t)row * NQ + q] = (float)bi;
            atomicAdd(&counts[bi], 1u);
        }
    }
}

// -------- gather + residual update + commit + bf16 emit for next layer ----
// grid 256 blocks (64 rows each), 256 threads
__global__ __launch_bounds__(256) void vq_update(
    const float* __restrict__ src,    // residual before (x for q=0), (B,C,T)
    float* __restrict__ dst,          // residual after (d_out qout slot)
    const float* __restrict__ cb,
    const int* __restrict__ best_idx,
    float* __restrict__ commit_slot,
    unsigned short* __restrict__ xhi, // bf16 residual for next layer's dist
    unsigned short* __restrict__ xlo)
{
    const int rb = blockIdx.x, tid = threadIdx.x;
    const int b = rb >> 2, t0 = (rb & 3) << 6;
    const int row0 = rb * 64;                    // = b*256 + t0
    __shared__ int s_idx[64];
    __shared__ __align__(16) float qt[64][68];   // [c_local][t_local]
    __shared__ float wsum[4];
    if (tid < 64) s_idx[tid] = best_idx[row0 + tid];
    __syncthreads();
    float csum = 0.f;
    const size_t base = (size_t)b * (NC * NT) + t0;
    for (int ct = 0; ct < 8; ++ct) {             // c chunks of 64
        if (ct) __syncthreads();
        // gather cb[idx[r]] chunk into qt [c][t]
        #pragma unroll
        for (int i = 0; i < 4; ++i) {
            int f = tid + (i << 8);
            int r = f >> 4, cf = f & 15;
            float4 v = *(const float4*)(cb + (size_t)s_idx[r] * NC + ct * 64 + (cf << 2));
            qt[(cf << 2) + 0][r] = v.x;
            qt[(cf << 2) + 1][r] = v.y;
            qt[(cf << 2) + 2][r] = v.z;
            qt[(cf << 2) + 3][r] = v.w;
        }
        __syncthreads();
        // residual RMW (coalesced along t); overwrite qt cells with n in place
        #pragma unroll
        for (int i = 0; i < 4; ++i) {
            int f = tid + (i << 8);
            int c_l = f >> 4, tf = f & 15;
            size_t o = base + (size_t)(ct * 64 + c_l) * NT + (tf << 2);
            float4 r4 = *(const float4*)(src + o);
            float4 q4 = *(const float4*)&qt[c_l][tf << 2];
            float4 n;
            n.x = r4.x - q4.x; n.y = r4.y - q4.y; n.z = r4.z - q4.z; n.w = r4.w - q4.w;
            *(float4*)(dst + o) = n;
            *(float4*)&qt[c_l][tf << 2] = n;
            csum += n.x*n.x + n.y*n.y + n.z*n.z + n.w*n.w;
        }
        __syncthreads();
        // transpose-read n and emit bf16 hi/lo in (r,c) layout
        #pragma unroll
        for (int i = 0; i < 4; ++i) {
            int f = tid + (i << 8);
            int r_l = f >> 4, c4 = f & 15;
            ushort4 hh, ll;
            unsigned short* hp = &hh.x; unsigned short* lp = &ll.x;
            #pragma unroll
            for (int j = 0; j < 4; ++j) {
                float v = qt[c4 * 4 + j][r_l];
                unsigned short h = f2bf(v);
                hp[j] = h; lp[j] = f2bf(v - bf2f(h));
            }
            size_t o = (size_t)(row0 + r_l) * NC + ct * 64 + (c4 << 2);
            *(ushort4*)(xhi + o) = hh;
            *(ushort4*)(xlo + o) = ll;
        }
    }
    #pragma unroll
    for (int off = 32; off; off >>= 1) csum += __shfl_down(csum, off, 64);
    if ((tid & 63) == 0) wsum[tid >> 6] = csum;
    __syncthreads();
    if (tid == 0) atomicAdd(commit_slot, wsum[0] + wsum[1] + wsum[2] + wsum[3]);
}

// -------- perplexity + commit mean per layer; final means at q==5 --------
__global__ void vq_stats(const unsigned int* __restrict__ counts,
                         float* __restrict__ csum, float* __restrict__ cmean,
                         float* __restrict__ perp, float* __restrict__ out_tail, int q)
{
    const int tid = threadIdx.x;   // 1024
    float p = (float)counts[tid] * (1.f / (float)NROWS);
    float v = p * logf(p + 1e-7f);
    #pragma unroll
    for (int off = 32; off; off >>= 1) v += __shfl_down(v, off, 64);
    __shared__ float red[16];
    if ((tid & 63) == 0) red[tid >> 6] = v;
    __syncthreads();
    if (tid == 0) {
        float S = 0.f;
        #pragma unroll
        for (int i = 0; i < 16; ++i) S += red[i];
        perp[q]  = expf(-S);
        cmean[q] = csum[q] * (1.f / ((float)NROWS * (float)NC));
        if (q == NQ - 1) {
            float mc = 0.f, mp = 0.f;
            for (int i = 0; i < NQ; ++i) { mc += cmean[i]; mp += perp[i]; }
            out_tail[0] = mc / (float)NQ;
            out_tail[1] = mp / (float)NQ;
        }
    }
}

// -------- qout = x - residual_final (elementwise, in place) --------
__global__ void vq_finalize(const float* __restrict__ x, float* __restrict__ res, int n4) {
    int i = blockIdx.x * blockDim.x + threadIdx.x;
    if (i < n4) {
        float4 a = ((const float4*)x)[i];
        float4 r = ((float4*)res)[i];
        float4 o;
        o.x = a.x - r.x; o.y = a.y - r.y; o.z = a.z - r.z; o.w = a.w - r.w;
        ((float4*)res)[i] = o;
    }
}

extern "C" void kernel_launch(void* const* d_in, const int* in_sizes, int n_in,
                              void* d_out, int out_size, void* d_ws, size_t ws_size,
                              hipStream_t stream) {
    const float* x  = (const float*)d_in[0];
    const float* cb = (const float*)d_in[1];       // (Q,K,C)
    float* out      = (float*)d_out;
    float* res      = out;                          // residual lives in qout slot
    float* out_idx  = out + QOUT_ELEMS;
    float* out_tail = out + QOUT_ELEMS + IDX_ELEMS;
    char* ws = (char*)d_ws;
    unsigned int* cand    = (unsigned int*)(ws + WS_CAND);
    unsigned int* candcnt = (unsigned int*)(ws + WS_CCNT);
    int*          bidx    = (int*)(ws + WS_BIDX);
    unsigned int* counts  = (unsigned int*)(ws + WS_COUNTS);
    float* csum  = (float*)(ws + WS_CSUM);
    float* cmean = (float*)(ws + WS_CMEAN);
    float* perp  = (float*)(ws + WS_PERP);
    float* cbn   = (float*)(ws + WS_CBN);
    unsigned short* xhi  = (unsigned short*)(ws + WS_XHI);
    unsigned short* xlo  = (unsigned short*)(ws + WS_XLO);
    unsigned short* cbhi = (unsigned short*)(ws + WS_CBHI);
    unsigned short* cblo = (unsigned short*)(ws + WS_CBLO);

    vq_cvt_cb<<<1536, 256, 0, stream>>>(cb, cbhi, cblo, cbn);
    vq_cvt_x<<<2048, 256, 0, stream>>>(x, xhi, xlo);
    for (int q = 0; q < NQ; ++q) {
        hipMemsetAsync(candcnt, 0, NROWS * sizeof(unsigned int), stream);
        const float* src = (q == 0) ? x : res;
        const float* cbq = cb + (size_t)q * NK * NC;
        vq_dist<<<dim3(128, 8), 256, 0, stream>>>(
            xhi, xlo, cbhi + (size_t)q * NK * NC, cblo + (size_t)q * NK * NC,
            cbn + q * NK, cand, candcnt, counts, csum + q);
        vq_rescore<<<1024, 256, 0, stream>>>(src, cbq, cbn + q * NK, cand, candcnt,
                                             bidx, out_idx, counts, q);
        vq_update<<<256, 256, 0, stream>>>(src, res, cbq, bidx, csum + q, xhi, xlo);
        vq_stats<<<1, 1024, 0, stream>>>(counts, csum, cmean, perp, out_tail, q);
    }
    vq_finalize<<<8192, 256, 0, stream>>>(x, res, QOUT_ELEMS / 4);
}

// Round 6
// 995.884 us; speedup vs baseline: 48.4560x; 1.1654x over previous
//
#include <hip/hip_runtime.h>

typedef short bf16x8 __attribute__((ext_vector_type(8)));
typedef float f32x4  __attribute__((ext_vector_type(4)));

// Problem constants
#define NB   64
#define NT   256
#define NC   512
#define NK   1024
#define NQ   6
#define NROWS (NB*NT)        // 16384
#define QOUT_ELEMS 8388608   // B*C*T
#define IDX_ELEMS  98304     // B*T*Q
#define DELTA 0.5f           // candidate window (~10x the 512-term bf16 approx error std)

// ws layout (bytes)
#define WS_CAND   0                        // u32[16384*32] = 2 MiB
#define WS_CCNT   0x200000                 // u32[16384]
#define WS_BIDX   0x210000                 // i32[16384]
#define WS_COUNTS 0x220000                 // u32[1024]
#define WS_CSUM   0x221000                 // f32[6]
#define WS_CMEAN  0x221020                 // f32[6]
#define WS_PERP   0x221040                 // f32[6]
#define WS_DONE   0x221060                 // u32[1]
#define WS_CBN    0x222000                 // f32[6144]
#define WS_XHI    0x230000                 // ushort[16384*512], 16 MiB
#define WS_CBHI   (WS_XHI + 16777216)      // ushort[6144*512], 6 MiB

// bf16 helpers (RNE; data is gaussian, no inf/nan)
__device__ __forceinline__ unsigned short f2bf(float f) {
    unsigned u = __float_as_uint(f);
    return (unsigned short)((u + 0x7FFFu + ((u >> 16) & 1u)) >> 16);
}

__device__ __forceinline__ void load_lds16(const unsigned short* g, unsigned short* l) {
    __builtin_amdgcn_global_load_lds(
        (const __attribute__((address_space(1))) unsigned int*)g,
        (__attribute__((address_space(3))) unsigned int*)l,
        16, 0, 0);
}

// -------- codebook conversion (all 6 layers) + half-norms --------
__global__ __launch_bounds__(256) void vq_cvt_cb(const float* __restrict__ cb,
                                                 unsigned short* __restrict__ cbhi,
                                                 float* __restrict__ cbn) {
    int lane = threadIdx.x & 63, wid = threadIdx.x >> 6;
    int code = blockIdx.x * 4 + wid;                 // 0..6143
    const float* row = cb + (size_t)code * NC;
    float4 v0 = *(const float4*)(row + lane * 8);
    float4 v1 = *(const float4*)(row + lane * 8 + 4);
    float vs[8] = {v0.x, v0.y, v0.z, v0.w, v1.x, v1.y, v1.z, v1.w};
    ushort4 a, b;
    unsigned short* ap = &a.x; unsigned short* bp = &b.x;
    float s = 0.f;
    #pragma unroll
    for (int j = 0; j < 4; ++j) {
        s += vs[j] * vs[j] + vs[j+4] * vs[j+4];
        ap[j] = f2bf(vs[j]); bp[j] = f2bf(vs[j+4]);
    }
    size_t o = (size_t)code * NC + lane * 8;
    *(ushort4*)(cbhi + o) = a; *(ushort4*)(cbhi + o + 4) = b;
    #pragma unroll
    for (int off = 32; off; off >>= 1) s += __shfl_down(s, off, 64);
    if (lane == 0) cbn[code] = 0.5f * s;
}

// -------- x conversion: (B,C,T) fp32 -> (r=b*T+t, c) bf16; also zero flags ----
__global__ __launch_bounds__(256) void vq_cvt_x(const float* __restrict__ x,
                                                unsigned short* __restrict__ xh,
                                                unsigned int* __restrict__ candcnt,
                                                unsigned int* __restrict__ done) {
    __shared__ unsigned short hs[64][72];
    int bx = blockIdx.x;
    int b = bx >> 5, tt = (bx >> 3) & 3, c0 = (bx & 7) << 6;
    int t0 = tt << 6, tid = threadIdx.x;
    if ((bx & 7) == 0 && tid < 64) candcnt[b * 256 + t0 + tid] = 0u;  // layer-0 init
    if (bx == 0 && tid == 0) *done = 0u;
    const float* base = x + (size_t)b * (NC * NT) + t0;
    #pragma unroll
    for (int i = 0; i < 4; ++i) {
        int f = tid + (i << 8);
        int c_l = f >> 4, t4 = f & 15;
        float4 v = *(const float4*)(base + (size_t)(c0 + c_l) * NT + (t4 << 2));
        ushort4 hh;
        hh.x = f2bf(v.x); hh.y = f2bf(v.y); hh.z = f2bf(v.z); hh.w = f2bf(v.w);
        *(ushort4*)&hs[c_l][t4 << 2] = hh;
    }
    __syncthreads();
    int row0 = b * NT + t0;
    #pragma unroll
    for (int i = 0; i < 4; ++i) {
        int f = tid + (i << 8);
        int r_l = f >> 4, c4 = f & 15;
        ushort4 hh;
        hh.x = hs[c4*4+0][r_l]; hh.y = hs[c4*4+1][r_l];
        hh.z = hs[c4*4+2][r_l]; hh.w = hs[c4*4+3][r_l];
        *(ushort4*)(xh + (size_t)(row0 + r_l) * NC + c0 + (c4 << 2)) = hh;
    }
}

// -------- bf16 MFMA approx distance + candidate emission --------
// grid (128 rowblocks, 8 codegroups), 256 threads = 4 waves, 64x64 per wave.
// BK=64, XOR-swizzled LDS: chunk (16B) of row r stored at slot q^(r&7)
// -> conflict-free ds_read_b128 AND legal global_load_lds dest (base+lane*16).
__global__ __launch_bounds__(256) void vq_dist(
    const unsigned short* __restrict__ xh, const unsigned short* __restrict__ ch,
    const float* __restrict__ cbn,
    unsigned int* __restrict__ cand, unsigned int* __restrict__ candcnt,
    unsigned int* __restrict__ counts, float* __restrict__ commit_slot)
{
    const int rb = blockIdx.x, cg = blockIdx.y, tid = threadIdx.x;
    if (rb == 0 && cg == 0) {     // init for rescore/update of this layer
        for (int i = tid; i < NK; i += 256) counts[i] = 0u;
        if (tid == 0) *commit_slot = 0.f;
    }
    __shared__ unsigned short smem[16384];   // A: [0,8192) rows 0..127 x 64, B: [8192,16384)
    const int wave = tid >> 6, lane = tid & 63;
    const int idx16 = lane & 15, quad = lane >> 4;
    const int wm = wave >> 1, wn = wave & 1;
    const int m0 = rb * 128, n0 = cg * 128;

    // staging: waves 0,1 -> A (xh rows m0..), waves 2,3 -> B (ch rows n0..)
    const unsigned short* gsrc = (wave < 2) ? xh : ch;
    const int rbase = (wave < 2) ? m0 : n0;
    const int wseg  = (wave & 1) * 64;
    const int srow  = wseg + (lane >> 3);                 // row in tile (per instr i: +8i)
    const int sq    = (lane & 7) ^ ((lane >> 3) & 7);     // swizzled source chunk
    const unsigned short* gp = gsrc + (size_t)(rbase + srow) * NC + sq * 8;
    unsigned short* lp = &smem[((wave >= 2) ? 8192 : 0) + wseg * 64 + lane * 8];

    f32x4 acc[4][4];
    #pragma unroll
    for (int a = 0; a < 4; ++a)
        #pragma unroll
        for (int c = 0; c < 4; ++c) acc[a][c] = (f32x4){0.f, 0.f, 0.f, 0.f};

    for (int cc = 0; cc < NC; cc += 64) {
        __syncthreads();
        #pragma unroll
        for (int i = 0; i < 8; ++i)
            load_lds16(gp + (size_t)(i * 8) * NC + cc, lp + i * 512);
        __syncthreads();
        #pragma unroll
        for (int ks = 0; ks < 2; ++ks) {
            bf16x8 a[4], b[4];
            #pragma unroll
            for (int mt = 0; mt < 4; ++mt) {
                int r = wm * 64 + mt * 16 + idx16;
                a[mt] = *(const bf16x8*)&smem[r * 64 + (((quad + 4*ks) ^ (r & 7)) << 3)];
            }
            #pragma unroll
            for (int nt = 0; nt < 4; ++nt) {
                int r = wn * 64 + nt * 16 + idx16;
                b[nt] = *(const bf16x8*)&smem[8192 + r * 64 + (((quad + 4*ks) ^ (r & 7)) << 3)];
            }
            #pragma unroll
            for (int mt = 0; mt < 4; ++mt)
                #pragma unroll
                for (int nt = 0; nt < 4; ++nt)
                    acc[mt][nt] = __builtin_amdgcn_mfma_f32_16x16x32_bf16(a[mt], b[nt], acc[mt][nt], 0, 0, 0);
        }
    }
    // epilogue: per-row wave-min over this wave's 64 codes, delta-window emission
    float cn[4]; int ng[4];
    #pragma unroll
    for (int nt = 0; nt < 4; ++nt) {
        ng[nt] = n0 + wn * 64 + nt * 16 + idx16;
        cn[nt] = cbn[ng[nt]];
    }
    #pragma unroll
    for (int mt = 0; mt < 4; ++mt) {
        #pragma unroll
        for (int r = 0; r < 4; ++r) {
            float sc[4];
            float m = 3.402823466e38f;
            #pragma unroll
            for (int nt = 0; nt < 4; ++nt) {
                sc[nt] = cn[nt] - acc[mt][nt][r];
                m = fminf(m, sc[nt]);
            }
            #pragma unroll
            for (int sft = 1; sft < 16; sft <<= 1)
                m = fminf(m, __shfl_xor(m, sft, 64));
            m += DELTA;
            const int row = m0 + wm * 64 + mt * 16 + quad * 4 + r;
            #pragma unroll
            for (int nt = 0; nt < 4; ++nt) {
                if (sc[nt] <= m) {
                    unsigned slot = atomicAdd(&candcnt[row], 1u);
                    if (slot < 32u) cand[(size_t)row * 32 + slot] = (unsigned)ng[nt];
                }
            }
        }
    }
}

// -------- exact fp32 rescore of candidates: final argmin + histogram --------
// grid 1024 blocks (16 rows each), 256 threads = 4 waves, 4 rows/wave.
__global__ __launch_bounds__(256) void vq_rescore(
    const float* __restrict__ src,     // residual (B,C,T) current layer input
    const float* __restrict__ cb, const float* __restrict__ cbn,
    const unsigned int* __restrict__ cand, const unsigned int* __restrict__ candcnt,
    int* __restrict__ best_idx, float* __restrict__ out_idx,
    unsigned int* __restrict__ counts, int q)
{
    __shared__ float xl[16][512];      // [t_local][c], 32 KiB
    const int tid = threadIdx.x;
    const int b = blockIdx.x >> 4, t0 = (blockIdx.x & 15) << 4;
    const float* base = src + (size_t)b * (NC * NT) + t0;
    #pragma unroll
    for (int i = 0; i < 8; ++i) {
        int f = tid + (i << 8);
        int c = f >> 2, t4 = f & 3;
        float4 v = *(const float4*)(base + (size_t)c * NT + (t4 << 2));
        xl[(t4 << 2) + 0][c] = v.x; xl[(t4 << 2) + 1][c] = v.y;
        xl[(t4 << 2) + 2][c] = v.z; xl[(t4 << 2) + 3][c] = v.w;
    }
    __syncthreads();
    const int w = tid >> 6, lane = tid & 63;
    const int row0 = b * NT + t0;
    for (int rr = 0; rr < 4; ++rr) {
        const int tl = w * 4 + rr;
        const int row = row0 + tl;
        float4 xa = *(const float4*)&xl[tl][lane << 3];
        float4 xb = *(const float4*)&xl[tl][(lane << 3) + 4];
        int n = (int)candcnt[row]; if (n > 32) n = 32;
        float bs = 3.402823466e38f; int bi = 0x7FFFFFFF;
        for (int j = 0; j < n; ++j) {
            int code = (int)cand[(size_t)row * 32 + j];
            const float* cr = cb + (size_t)code * NC + (lane << 3);
            float4 ca = *(const float4*)cr;
            float4 cc = *(const float4*)(cr + 4);
            float s = xa.x*ca.x + xa.y*ca.y + xa.z*ca.z + xa.w*ca.w
                    + xb.x*cc.x + xb.y*cc.y + xb.z*cc.z + xb.w*cc.w;
            #pragma unroll
            for (int off = 1; off < 64; off <<= 1) s += __shfl_xor(s, off, 64);
            s = cbn[code] - s;
            if (s < bs || (s == bs && code < bi)) { bs = s; bi = code; }
        }
        if (lane == 0) {
            best_idx[row] = bi;
            out_idx[(size_t)row * NQ + q] = (float)bi;
            atomicAdd(&counts[bi], 1u);
        }
    }
}

// -------- gather + residual update + commit + bf16 emit + FUSED stats --------
// grid 256 blocks (64 rows each), 256 threads; last block computes perp/cmean.
__global__ __launch_bounds__(256) void vq_update(
    const float* __restrict__ src,    // residual before (x for q=0), (B,C,T)
    float* __restrict__ dst,          // residual after (d_out qout slot)
    const float* __restrict__ cb,
    const int* __restrict__ best_idx,
    unsigned short* __restrict__ xh,  // bf16 residual for next layer's dist
    unsigned int* __restrict__ candcnt,
    unsigned int* __restrict__ counts,
    float* __restrict__ csum, float* __restrict__ cmean, float* __restrict__ perp,
    float* __restrict__ out_tail, unsigned int* __restrict__ done, int q)
{
    const int rb = blockIdx.x, tid = threadIdx.x;
    const int b = rb >> 2, t0 = (rb & 3) << 6;
    const int row0 = rb * 64;                    // = b*256 + t0
    __shared__ int s_idx[64];
    __shared__ __align__(16) float qt[64][68];   // [c_local][t_local]
    __shared__ float wsum[4];
    __shared__ unsigned int lastflag;
    if (tid < 64) {
        s_idx[tid] = best_idx[row0 + tid];
        candcnt[row0 + tid] = 0u;                // reset for next layer's dist
    }
    __syncthreads();
    float cs = 0.f;
    const size_t base = (size_t)b * (NC * NT) + t0;
    for (int ct = 0; ct < 8; ++ct) {             // c chunks of 64
        if (ct) __syncthreads();
        // gather cb[idx[r]] chunk into qt [c][t]
        #pragma unroll
        for (int i = 0; i < 4; ++i) {
            int f = tid + (i << 8);
            int r = f >> 4, cf = f & 15;
            float4 v = *(const float4*)(cb + (size_t)s_idx[r] * NC + ct * 64 + (cf << 2));
            qt[(cf << 2) + 0][r] = v.x;
            qt[(cf << 2) + 1][r] = v.y;
            qt[(cf << 2) + 2][r] = v.z;
            qt[(cf << 2) + 3][r] = v.w;
        }
        __syncthreads();
        // residual RMW (coalesced along t); overwrite qt cells with n in place
        #pragma unroll
        for (int i = 0; i < 4; ++i) {
            int f = tid + (i << 8);
            int c_l = f >> 4, tf = f & 15;
            size_t o = base + (size_t)(ct * 64 + c_l) * NT + (tf << 2);
            float4 r4 = *(const float4*)(src + o);
            float4 q4 = *(const float4*)&qt[c_l][tf << 2];
            float4 n;
            n.x = r4.x - q4.x; n.y = r4.y - q4.y; n.z = r4.z - q4.z; n.w = r4.w - q4.w;
            *(float4*)(dst + o) = n;
            *(float4*)&qt[c_l][tf << 2] = n;
            cs += n.x*n.x + n.y*n.y + n.z*n.z + n.w*n.w;
        }
        __syncthreads();
        // transpose-read n and emit bf16 in (r,c) layout
        #pragma unroll
        for (int i = 0; i < 4; ++i) {
            int f = tid + (i << 8);
            int r_l = f >> 4, c4 = f & 15;
            ushort4 hh;
            hh.x = f2bf(qt[c4*4+0][r_l]); hh.y = f2bf(qt[c4*4+1][r_l]);
            hh.z = f2bf(qt[c4*4+2][r_l]); hh.w = f2bf(qt[c4*4+3][r_l]);
            *(ushort4*)(xh + (size_t)(row0 + r_l) * NC + ct * 64 + (c4 << 2)) = hh;
        }
    }
    #pragma unroll
    for (int off = 32; off; off >>= 1) cs += __shfl_down(cs, off, 64);
    if ((tid & 63) == 0) wsum[tid >> 6] = cs;
    __syncthreads();
    if (tid == 0) {
        atomicAdd(&csum[q], wsum[0] + wsum[1] + wsum[2] + wsum[3]);
        __threadfence();
        lastflag = atomicAdd(done, 1u);
    }
    __syncthreads();
    if (lastflag == 255u) {                      // last block: fused per-layer stats
        float v = 0.f;
        for (int i = tid; i < NK; i += 256) {
            float p = (float)atomicAdd(&counts[i], 0u) * (1.f / (float)NROWS);
            v += p * logf(p + 1e-7f);
        }
        #pragma unroll
        for (int off = 32; off; off >>= 1) v += __shfl_down(v, off, 64);
        if ((tid & 63) == 0) wsum[tid >> 6] = v;
        __syncthreads();
        if (tid == 0) {
            float S = wsum[0] + wsum[1] + wsum[2] + wsum[3];
            perp[q]  = expf(-S);
            cmean[q] = atomicAdd(&csum[q], 0.f) * (1.f / ((float)NROWS * (float)NC));
            if (q == NQ - 1) {
                float mc = 0.f, mp = 0.f;
                for (int i = 0; i < NQ; ++i) { mc += cmean[i]; mp += perp[i]; }
                out_tail[0] = mc / (float)NQ;
                out_tail[1] = mp / (float)NQ;
            }
            *done = 0u;                          // reset for next layer
        }
    }
}

// -------- qout = x - residual_final (elementwise, in place) --------
__global__ void vq_finalize(const float* __restrict__ x, float* __restrict__ res, int n4) {
    int i = blockIdx.x * blockDim.x + threadIdx.x;
    if (i < n4) {
        float4 a = ((const float4*)x)[i];
        float4 r = ((float4*)res)[i];
        float4 o;
        o.x = a.x - r.x; o.y = a.y - r.y; o.z = a.z - r.z; o.w = a.w - r.w;
        ((float4*)res)[i] = o;
    }
}

extern "C" void kernel_launch(void* const* d_in, const int* in_sizes, int n_in,
                              void* d_out, int out_size, void* d_ws, size_t ws_size,
                              hipStream_t stream) {
    const float* x  = (const float*)d_in[0];
    const float* cb = (const float*)d_in[1];       // (Q,K,C)
    float* out      = (float*)d_out;
    float* res      = out;                          // residual lives in qout slot
    float* out_idx  = out + QOUT_ELEMS;
    float* out_tail = out + QOUT_ELEMS + IDX_ELEMS;
    char* ws = (char*)d_ws;
    unsigned int* cand    = (unsigned int*)(ws + WS_CAND);
    unsigned int* candcnt = (unsigned int*)(ws + WS_CCNT);
    int*          bidx    = (int*)(ws + WS_BIDX);
    unsigned int* counts  = (unsigned int*)(ws + WS_COUNTS);
    float* csum  = (float*)(ws + WS_CSUM);
    float* cmean = (float*)(ws + WS_CMEAN);
    float* perp  = (float*)(ws + WS_PERP);
    unsigned int* done = (unsigned int*)(ws + WS_DONE);
    float* cbn   = (float*)(ws + WS_CBN);
    unsigned short* xh   = (unsigned short*)(ws + WS_XHI);
    unsigned short* cbhi = (unsigned short*)(ws + WS_CBHI);

    vq_cvt_cb<<<1536, 256, 0, stream>>>(cb, cbhi, cbn);
    vq_cvt_x<<<2048, 256, 0, stream>>>(x, xh, candcnt, done);
    for (int q = 0; q < NQ; ++q) {
        const float* src = (q == 0) ? x : res;
        const float* cbq = cb + (size_t)q * NK * NC;
        vq_dist<<<dim3(128, 8), 256, 0, stream>>>(
            xh, cbhi + (size_t)q * NK * NC, cbn + q * NK,
            cand, candcnt, counts, csum + q);
        vq_rescore<<<1024, 256, 0, stream>>>(src, cbq, cbn + q * NK, cand, candcnt,
                                             bidx, out_idx, counts, q);
        vq_update<<<256, 256, 0, stream>>>(src, res, cbq, bidx, xh, candcnt,
                                           counts, csum, cmean, perp, out_tail, done, q);
    }
    vq_finalize<<<8192, 256, 0, stream>>>(x, res, QOUT_ELEMS / 4);
}